// Round 1
// baseline (1076.210 us; speedup 1.0000x reference)
//
#include <hip/hip_runtime.h>

// Problem constants (fixed by the reference): T=512, B=64, I=256, H=512.
#define T_DIM 512
#define B_DIM 64
#define I_DIM 256
#define H_DIM 512
#define BH_DIM (B_DIM * H_DIM)   // 32768

// ---------------------------------------------------------------------------
// Round-7: co-residency. 512 blocks = 8 row-chunks x 64 batches, 256 threads,
// 2 blocks/CU (LDS 71 KB/block, __launch_bounds__(256,2) caps regs at 256).
// Two independent blocks per CU interleave: one block's publish->detect dead
// window is filled by the other block's FMA issue.
//
// Per block:
//   - W_hh chunk (64 rows x 512) in registers: w[4][8] float4 / thread.
//   - W_ih chunk (64 rows x 256) in LDS (64 KB), loaded once.
//   - x_t (256 floats) prefetched distance-2 into a triple-buffered LDS slot.
// Per step t:
//   A. ih-matvec b0..b3 = W_ih . x_t  (LDS only, no h dependence) -- runs
//      BEFORE the poll, hiding the publish->detect L2 round trip.
//   B. poll partners' tagged h_{t-1} words into hbuf. 224 threads x 1 PAIR
//      of adjacent 8-byte words each (448 partner elements). Tags packed
//      (tag=t, fp32); parity double-buffer is ABA-safe; relaxed agent scope.
//   C. barrier; store x_{t+2} prefetch to LDS.
//   D. hh-fma a0..a3 over hbuf; acc = a+b; 16-lane butterfly.
//   E. lanes cg<4 publish: h = relu(acc + bias) -> stage (tagged), out, hbuf.
//
// Thread map: rg = tid>>4 (0..15), cg = tid&15; rows j0..j0+3
// (j0 = rb*64 + rg*4); hh cols = float4 idx {i*16+cg, i=0..7};
// ih cols = float4 idx {i*16+cg, i=0..3}. Per-instruction lane->bank
// pattern identical to R5/R6 (measured SQ_LDS_BANK_CONFLICT = 0).
// Partner blocks of batch b are b+64k: 64%8==0 -> all on one XCD, so the
// publish/poll protocol stays within a single XCD's L2.
// ---------------------------------------------------------------------------
__global__ __launch_bounds__(256, 2) void rnn_fused(
    const float* __restrict__ x, const float* __restrict__ wih,
    const float* __restrict__ whh, const float* __restrict__ bih,
    const float* __restrict__ bhh, float* __restrict__ out,
    unsigned long long* __restrict__ stage) {
  __shared__ __align__(16) float4 wihs4[64 * 64];   // 64 KB: my W_ih rows
  __shared__ __align__(16) float hbuf[2][H_DIM];    // 4 KB: h double buffer
  __shared__ __align__(16) float4 xbuf4[3 * 64];    // 3 KB: x_t triple buffer

  const int b   = blockIdx.x & 63;
  const int rb  = blockIdx.x >> 6;       // row-chunk 0..7
  const int tid = threadIdx.x;           // 0..255
  const int rg  = tid >> 4;              // 0..15
  const int cg  = tid & 15;              // 0..15
  const int j0  = rb * 64 + rg * 4;      // first of my 4 rows

  // spin target: one PAIR of adjacent words per thread 0..223 (skip own chunk:
  // own rows are pairs [rb*32, rb*32+32)). 224 pairs = 448 partner elements.
  const int pjp = (tid < rb * 32) ? tid : tid + 32;  // pair index (tid<224)

  // ---- W_hh chunk -> registers (once) ----
  float4 w[4][8];
#pragma unroll
  for (int r = 0; r < 4; r++) {
    const float4* wr = (const float4*)(whh + (size_t)(j0 + r) * H_DIM);
#pragma unroll
    for (int i = 0; i < 8; i++) w[r][i] = wr[i * 16 + cg];
  }

  // ---- W_ih chunk -> LDS (once; coalesced: linear float4 index) ----
  {
    const float4* wg = (const float4*)(wih + (size_t)rb * 64 * I_DIM);
#pragma unroll
    for (int q = 0; q < 16; q++) {
      const int idx = q * 256 + tid;  // 0..4095 = row*64 + c4
      wihs4[idx] = wg[idx];
    }
  }

  // ---- x_0, x_1 preload ----
  const float4* xg = (const float4*)x;  // idx = (t*B_DIM + b)*64 + c4
  if (tid < 64) {
    xbuf4[0 * 64 + tid] = xg[((size_t)0 * B_DIM + b) * 64 + tid];
    xbuf4[1 * 64 + tid] = xg[((size_t)1 * B_DIM + b) * 64 + tid];
  }

  // ---- bias for publishing lanes ----
  float bias = 0.f;
  if (cg < 4) bias = bih[j0 + cg] + bhh[j0 + cg];

  float* __restrict__ outb = out + (size_t)b * H_DIM;  // t-stride = BH_DIM
  unsigned long long* __restrict__ stg0 = stage + (size_t)b * H_DIM;
  unsigned long long* __restrict__ stg1 = stage + (size_t)(64 + b) * H_DIM;

  __syncthreads();  // W_ih, x0, x1 staged

  float hlast = 0.f;

  // ---- t = 0: h_0 = relu(W_ih x_0 + bias); publish (tag 0, parity 0) ----
  {
    float b0 = 0.f, b1 = 0.f, b2 = 0.f, b3 = 0.f;
    const float4* xb = &xbuf4[0];
    const float4* wr = &wihs4[(rg * 4) * 64];
#pragma unroll
    for (int i = 0; i < 4; i++) {
      const float4 xv = xb[i * 16 + cg];
      const float4 q0 = wr[0 * 64 + i * 16 + cg];
      const float4 q1 = wr[1 * 64 + i * 16 + cg];
      const float4 q2 = wr[2 * 64 + i * 16 + cg];
      const float4 q3 = wr[3 * 64 + i * 16 + cg];
      b0 = fmaf(q0.x, xv.x, b0); b0 = fmaf(q0.y, xv.y, b0);
      b0 = fmaf(q0.z, xv.z, b0); b0 = fmaf(q0.w, xv.w, b0);
      b1 = fmaf(q1.x, xv.x, b1); b1 = fmaf(q1.y, xv.y, b1);
      b1 = fmaf(q1.z, xv.z, b1); b1 = fmaf(q1.w, xv.w, b1);
      b2 = fmaf(q2.x, xv.x, b2); b2 = fmaf(q2.y, xv.y, b2);
      b2 = fmaf(q2.z, xv.z, b2); b2 = fmaf(q2.w, xv.w, b2);
      b3 = fmaf(q3.x, xv.x, b3); b3 = fmaf(q3.y, xv.y, b3);
      b3 = fmaf(q3.z, xv.z, b3); b3 = fmaf(q3.w, xv.w, b3);
    }
#pragma unroll
    for (int m = 1; m <= 8; m <<= 1) {
      b0 += __shfl_xor(b0, m, 64);
      b1 += __shfl_xor(b1, m, 64);
      b2 += __shfl_xor(b2, m, 64);
      b3 += __shfl_xor(b3, m, 64);
    }
    if (cg < 4) {
      const float acc = (cg == 0) ? b0 : (cg == 1) ? b1 : (cg == 2) ? b2 : b3;
      const float h = fmaxf(acc + bias, 0.f);
      const int j = j0 + cg;
      union { float f; unsigned int u; } cv; cv.f = h;
      __hip_atomic_store(&stg0[j], (unsigned long long)cv.u,
                         __ATOMIC_RELAXED, __HIP_MEMORY_SCOPE_AGENT);
      outb[j] = h;
      hbuf[0][j] = h;
      hlast = h;
    }
    // prefetch x_2 -> slot 2 (slot has no prior readers)
    if (tid < 64) {
      xbuf4[2 * 64 + tid] = xg[((size_t)2 * B_DIM + b) * 64 + tid];
    }
  }

  // ---- main scan ----
  for (int t = 1; t < T_DIM; t++) {
    const int p = (t - 1) & 1;  // parity of h_{t-1}
    float* hb = hbuf[p];
    float* o_t = outb + (size_t)t * BH_DIM;

    // A. ih-matvec on x_t (no h dependence; overlaps partners' publish->L2)
    float b0 = 0.f, b1 = 0.f, b2 = 0.f, b3 = 0.f;
    {
      const float4* xb = &xbuf4[(t % 3) * 64];
      const float4* wr = &wihs4[(rg * 4) * 64];
#pragma unroll
      for (int i = 0; i < 4; i++) {
        const float4 xv = xb[i * 16 + cg];
        const float4 q0 = wr[0 * 64 + i * 16 + cg];
        const float4 q1 = wr[1 * 64 + i * 16 + cg];
        const float4 q2 = wr[2 * 64 + i * 16 + cg];
        const float4 q3 = wr[3 * 64 + i * 16 + cg];
        b0 = fmaf(q0.x, xv.x, b0); b0 = fmaf(q0.y, xv.y, b0);
        b0 = fmaf(q0.z, xv.z, b0); b0 = fmaf(q0.w, xv.w, b0);
        b1 = fmaf(q1.x, xv.x, b1); b1 = fmaf(q1.y, xv.y, b1);
        b1 = fmaf(q1.z, xv.z, b1); b1 = fmaf(q1.w, xv.w, b1);
        b2 = fmaf(q2.x, xv.x, b2); b2 = fmaf(q2.y, xv.y, b2);
        b2 = fmaf(q2.z, xv.z, b2); b2 = fmaf(q2.w, xv.w, b2);
        b3 = fmaf(q3.x, xv.x, b3); b3 = fmaf(q3.y, xv.y, b3);
        b3 = fmaf(q3.z, xv.z, b3); b3 = fmaf(q3.w, xv.w, b3);
      }
    }

    // issue x_{t+2} global load early (latency off-path)
    float4 xpf = make_float4(0.f, 0.f, 0.f, 0.f);
    const bool do_pf = (tid < 64) && (t + 2 < T_DIM);
    if (do_pf) xpf = xg[((size_t)(t + 2) * B_DIM + b) * 64 + tid];

    // B. spin-collect the 448 partner elements of h_{t-1} into LDS (pairs)
    if (tid < 224) {
      unsigned long long* slot = (p ? stg1 : stg0) + 2 * pjp;
      const unsigned int want = (unsigned int)(t - 1);
      unsigned long long v0, v1;
      do {
        v0 = __hip_atomic_load(slot, __ATOMIC_RELAXED,
                               __HIP_MEMORY_SCOPE_AGENT);
        v1 = __hip_atomic_load(slot + 1, __ATOMIC_RELAXED,
                               __HIP_MEMORY_SCOPE_AGENT);
      } while ((unsigned int)(v0 >> 32) != want ||
               (unsigned int)(v1 >> 32) != want);
      union { unsigned int u; float f; } c0, c1;
      c0.u = (unsigned int)v0; c1.u = (unsigned int)v1;
      hb[2 * pjp]     = c0.f;
      hb[2 * pjp + 1] = c1.f;
    }

    __syncthreads();  // h_{t-1} complete in LDS (single barrier per step)

    // C. commit x_{t+2} to its slot (readers are 2 barriers away)
    if (do_pf) xbuf4[((t + 2) % 3) * 64 + tid] = xpf;

    // D. hh-fma: 4 rows x 8 float4 per thread (W_hh in regs/AGPRs)
    float a0 = b0, a1 = b1, a2 = b2, a3 = b3;
#pragma unroll
    for (int i = 0; i < 8; i++) {
      const float4 hv = ((const float4*)hb)[i * 16 + cg];
      a0 = fmaf(w[0][i].x, hv.x, a0); a0 = fmaf(w[0][i].y, hv.y, a0);
      a0 = fmaf(w[0][i].z, hv.z, a0); a0 = fmaf(w[0][i].w, hv.w, a0);
      a1 = fmaf(w[1][i].x, hv.x, a1); a1 = fmaf(w[1][i].y, hv.y, a1);
      a1 = fmaf(w[1][i].z, hv.z, a1); a1 = fmaf(w[1][i].w, hv.w, a1);
      a2 = fmaf(w[2][i].x, hv.x, a2); a2 = fmaf(w[2][i].y, hv.y, a2);
      a2 = fmaf(w[2][i].z, hv.z, a2); a2 = fmaf(w[2][i].w, hv.w, a2);
      a3 = fmaf(w[3][i].x, hv.x, a3); a3 = fmaf(w[3][i].y, hv.y, a3);
      a3 = fmaf(w[3][i].z, hv.z, a3); a3 = fmaf(w[3][i].w, hv.w, a3);
    }
#pragma unroll
    for (int m = 1; m <= 8; m <<= 1) {
      a0 += __shfl_xor(a0, m, 64);
      a1 += __shfl_xor(a1, m, 64);
      a2 += __shfl_xor(a2, m, 64);
      a3 += __shfl_xor(a3, m, 64);
    }

    // E. publish h_t (16 contiguous tagged words per wave, one instruction)
    if (cg < 4) {
      const float acc = (cg == 0) ? a0 : (cg == 1) ? a1 : (cg == 2) ? a2 : a3;
      const float h = fmaxf(acc + bias, 0.f);
      const int j = j0 + cg;
      union { float f; unsigned int u; } cv; cv.f = h;
      const unsigned long long tag = (unsigned long long)(unsigned int)t << 32;
      unsigned long long* sb = (t & 1) ? stg1 : stg0;
      __hip_atomic_store(&sb[j], tag | cv.u,
                         __ATOMIC_RELAXED, __HIP_MEMORY_SCOPE_AGENT);
      o_t[j] = h;            // output[t,b,j]
      hbuf[t & 1][j] = h;    // own rows for next step
      hlast = h;
    }
  }

  // h_final = h_{T-1}
  if (cg < 4) {
    out[(size_t)T_DIM * BH_DIM + (size_t)b * H_DIM + j0 + cg] = hlast;
  }
}

extern "C" void kernel_launch(void* const* d_in, const int* in_sizes, int n_in,
                              void* d_out, int out_size, void* d_ws, size_t ws_size,
                              hipStream_t stream) {
  const float* x   = (const float*)d_in[0];  // [T,B,I]
  const float* wih = (const float*)d_in[1];  // [H,I]
  const float* whh = (const float*)d_in[2];  // [H,H]
  const float* bih = (const float*)d_in[3];  // [H]
  const float* bhh = (const float*)d_in[4];  // [H]
  float* out = (float*)d_out;                // [T,B,H] output ++ [B,H] h_final
  // staging: 2 parities x 64 batches x 512 tagged 8B words = 512 KB
  unsigned long long* stage = (unsigned long long*)d_ws;

  rnn_fused<<<512, 256, 0, stream>>>(x, wih, whh, bih, bhh, out, stage);
}

// Round 2
// 981.093 us; speedup vs baseline: 1.0970x; 1.0970x over previous
//
#include <hip/hip_runtime.h>

// Problem constants (fixed by the reference): T=512, B=64, I=256, H=512.
#define T_DIM 512
#define B_DIM 64
#define I_DIM 256
#define H_DIM 512
#define BH_DIM (B_DIM * H_DIM)   // 32768

// ---------------------------------------------------------------------------
// Round-8: R6 structure (256 blocks = 4 row-chunks x 64 batches, 512 threads,
// 1 block/CU) + NON-TEMPORAL streaming traffic.
//
// R7 post-mortem: 8-way split regressed (worse convoy, same wave count).
// R6 counters show FETCH 99 MB vs 33 MB ideal and WRITE 196 MB: the 64 MB
// out[] stream + 32 MB x stream evict the stage lines from L2, so the
// slowest-of-384 poll regularly misses to HBM (~900 cyc) instead of hitting
// L2 (~200 cyc) -- that miss gates the per-step barrier. Fix: mark out[]
// stores and x loads non-temporal (no L2 allocate) so stage stays resident.
// Stage loads/stores remain normal (they MUST live in L2).
//
// Everything else identical to R6 (939 us):
//   - W_hh chunk (128 rows x 512) in registers: w[4][8] float4 / thread.
//   - W_ih chunk (128 rows x 256) in LDS (128 KB), loaded once.
//   - x_t prefetched distance-2 into a triple-buffered LDS slot.
//   - R5 tagged-word publish/poll protocol, parity double-buffer, relaxed
//     agent-scope atomics, single barrier per step.
// ---------------------------------------------------------------------------

typedef float f32x4_t __attribute__((ext_vector_type(4)));

__device__ __forceinline__ float4 nt_load4(const float4* p) {
  f32x4_t v = __builtin_nontemporal_load((const f32x4_t*)p);
  return make_float4(v.x, v.y, v.z, v.w);
}

__global__ __launch_bounds__(512, 2) void rnn_fused(
    const float* __restrict__ x, const float* __restrict__ wih,
    const float* __restrict__ whh, const float* __restrict__ bih,
    const float* __restrict__ bhh, float* __restrict__ out,
    unsigned long long* __restrict__ stage) {
  __shared__ __align__(16) float4 wihs4[128 * 64];  // 128 KB: my W_ih rows
  __shared__ __align__(16) float hbuf[2][H_DIM];    // 4 KB: h double buffer
  __shared__ __align__(16) float4 xbuf4[3 * 64];    // 3 KB: x_t triple buffer

  const int b   = blockIdx.x & 63;
  const int rb  = blockIdx.x >> 6;       // row-chunk 0..3
  const int tid = threadIdx.x;           // 0..511
  const int rg  = tid >> 4;              // 0..31
  const int cg  = tid & 15;              // 0..15
  const int j0  = rb * 128 + rg * 4;     // first of my 4 rows

  // spin target: one partner element each for threads 0..383 (skip own chunk)
  const int pj = (tid < rb * 128) ? tid : tid + 128;

  // ---- W_hh chunk -> registers (once) ----
  float4 w[4][8];
#pragma unroll
  for (int r = 0; r < 4; r++) {
    const float4* wr = (const float4*)(whh + (size_t)(j0 + r) * H_DIM);
#pragma unroll
    for (int i = 0; i < 8; i++) w[r][i] = wr[i * 16 + cg];
  }

  // ---- W_ih chunk -> LDS (once; coalesced: linear float4 index) ----
  {
    const float4* wg = (const float4*)(wih + (size_t)rb * 128 * I_DIM);
#pragma unroll
    for (int q = 0; q < 16; q++) {
      const int idx = q * 512 + tid;  // 0..8191 = row*64 + c4
      wihs4[idx] = wg[idx];
    }
  }

  // ---- x_0, x_1 preload (non-temporal: read-once stream) ----
  const float4* xg = (const float4*)x;  // idx = (t*B_DIM + b)*64 + c4
  if (tid < 64) {
    xbuf4[0 * 64 + tid] = nt_load4(&xg[((size_t)0 * B_DIM + b) * 64 + tid]);
    xbuf4[1 * 64 + tid] = nt_load4(&xg[((size_t)1 * B_DIM + b) * 64 + tid]);
  }

  // ---- bias for publishing lanes ----
  float bias = 0.f;
  if (cg < 4) bias = bih[j0 + cg] + bhh[j0 + cg];

  float* __restrict__ outb = out + (size_t)b * H_DIM;  // t-stride = BH_DIM
  unsigned long long* __restrict__ stg0 = stage + (size_t)b * H_DIM;
  unsigned long long* __restrict__ stg1 = stage + (size_t)(64 + b) * H_DIM;

  __syncthreads();  // W_ih, x0, x1 staged

  float hlast = 0.f;

  // ---- t = 0: h_0 = relu(W_ih x_0 + bias); publish (tag 0, parity 0) ----
  {
    float b0 = 0.f, b1 = 0.f, b2 = 0.f, b3 = 0.f;
    const float4* xb = &xbuf4[0];
    const float4* wr = &wihs4[(rg * 4) * 64];
#pragma unroll
    for (int i = 0; i < 4; i++) {
      const float4 xv = xb[i * 16 + cg];
      const float4 q0 = wr[0 * 64 + i * 16 + cg];
      const float4 q1 = wr[1 * 64 + i * 16 + cg];
      const float4 q2 = wr[2 * 64 + i * 16 + cg];
      const float4 q3 = wr[3 * 64 + i * 16 + cg];
      b0 = fmaf(q0.x, xv.x, b0); b0 = fmaf(q0.y, xv.y, b0);
      b0 = fmaf(q0.z, xv.z, b0); b0 = fmaf(q0.w, xv.w, b0);
      b1 = fmaf(q1.x, xv.x, b1); b1 = fmaf(q1.y, xv.y, b1);
      b1 = fmaf(q1.z, xv.z, b1); b1 = fmaf(q1.w, xv.w, b1);
      b2 = fmaf(q2.x, xv.x, b2); b2 = fmaf(q2.y, xv.y, b2);
      b2 = fmaf(q2.z, xv.z, b2); b2 = fmaf(q2.w, xv.w, b2);
      b3 = fmaf(q3.x, xv.x, b3); b3 = fmaf(q3.y, xv.y, b3);
      b3 = fmaf(q3.z, xv.z, b3); b3 = fmaf(q3.w, xv.w, b3);
    }
#pragma unroll
    for (int m = 1; m <= 8; m <<= 1) {
      b0 += __shfl_xor(b0, m, 64);
      b1 += __shfl_xor(b1, m, 64);
      b2 += __shfl_xor(b2, m, 64);
      b3 += __shfl_xor(b3, m, 64);
    }
    if (cg < 4) {
      const float acc = (cg == 0) ? b0 : (cg == 1) ? b1 : (cg == 2) ? b2 : b3;
      const float h = fmaxf(acc + bias, 0.f);
      const int j = j0 + cg;
      union { float f; unsigned int u; } cv; cv.f = h;
      __hip_atomic_store(&stg0[j], (unsigned long long)cv.u,
                         __ATOMIC_RELAXED, __HIP_MEMORY_SCOPE_AGENT);
      __builtin_nontemporal_store(h, &outb[j]);
      hbuf[0][j] = h;
      hlast = h;
    }
    // prefetch x_2 -> slot 2 (slot has no prior readers)
    if (tid < 64) {
      xbuf4[2 * 64 + tid] = nt_load4(&xg[((size_t)2 * B_DIM + b) * 64 + tid]);
    }
  }

  // ---- main scan ----
  for (int t = 1; t < T_DIM; t++) {
    const int p = (t - 1) & 1;  // parity of h_{t-1}
    float* hb = hbuf[p];
    float* o_t = outb + (size_t)t * BH_DIM;

    // A. ih-matvec on x_t (no h dependence; overlaps partners' publish->L2)
    float b0 = 0.f, b1 = 0.f, b2 = 0.f, b3 = 0.f;
    {
      const float4* xb = &xbuf4[(t % 3) * 64];
      const float4* wr = &wihs4[(rg * 4) * 64];
#pragma unroll
      for (int i = 0; i < 4; i++) {
        const float4 xv = xb[i * 16 + cg];
        const float4 q0 = wr[0 * 64 + i * 16 + cg];
        const float4 q1 = wr[1 * 64 + i * 16 + cg];
        const float4 q2 = wr[2 * 64 + i * 16 + cg];
        const float4 q3 = wr[3 * 64 + i * 16 + cg];
        b0 = fmaf(q0.x, xv.x, b0); b0 = fmaf(q0.y, xv.y, b0);
        b0 = fmaf(q0.z, xv.z, b0); b0 = fmaf(q0.w, xv.w, b0);
        b1 = fmaf(q1.x, xv.x, b1); b1 = fmaf(q1.y, xv.y, b1);
        b1 = fmaf(q1.z, xv.z, b1); b1 = fmaf(q1.w, xv.w, b1);
        b2 = fmaf(q2.x, xv.x, b2); b2 = fmaf(q2.y, xv.y, b2);
        b2 = fmaf(q2.z, xv.z, b2); b2 = fmaf(q2.w, xv.w, b2);
        b3 = fmaf(q3.x, xv.x, b3); b3 = fmaf(q3.y, xv.y, b3);
        b3 = fmaf(q3.z, xv.z, b3); b3 = fmaf(q3.w, xv.w, b3);
      }
    }

    // issue x_{t+2} global load early (latency off-path; non-temporal)
    float4 xpf = make_float4(0.f, 0.f, 0.f, 0.f);
    const bool do_pf = (tid < 64) && (t + 2 < T_DIM);
    if (do_pf) xpf = nt_load4(&xg[((size_t)(t + 2) * B_DIM + b) * 64 + tid]);

    // B. spin-collect the 384 partner elements of h_{t-1} into LDS
    if (tid < 384) {
      unsigned long long* slot = (p ? stg1 : stg0) + pj;
      const unsigned int want = (unsigned int)(t - 1);
      unsigned long long v;
      do {
        v = __hip_atomic_load(slot, __ATOMIC_RELAXED, __HIP_MEMORY_SCOPE_AGENT);
      } while ((unsigned int)(v >> 32) != want);
      union { unsigned int u; float f; } cv; cv.u = (unsigned int)v;
      hb[pj] = cv.f;
    }

    __syncthreads();  // h_{t-1} complete in LDS (single barrier per step)

    // C. commit x_{t+2} to its slot (readers are 2 barriers away)
    if (do_pf) xbuf4[((t + 2) % 3) * 64 + tid] = xpf;

    // D. hh-fma: 4 rows x 8 float4 per thread (W_hh in regs/AGPRs)
    float a0 = b0, a1 = b1, a2 = b2, a3 = b3;
#pragma unroll
    for (int i = 0; i < 8; i++) {
      const float4 hv = ((const float4*)hb)[i * 16 + cg];
      a0 = fmaf(w[0][i].x, hv.x, a0); a0 = fmaf(w[0][i].y, hv.y, a0);
      a0 = fmaf(w[0][i].z, hv.z, a0); a0 = fmaf(w[0][i].w, hv.w, a0);
      a1 = fmaf(w[1][i].x, hv.x, a1); a1 = fmaf(w[1][i].y, hv.y, a1);
      a1 = fmaf(w[1][i].z, hv.z, a1); a1 = fmaf(w[1][i].w, hv.w, a1);
      a2 = fmaf(w[2][i].x, hv.x, a2); a2 = fmaf(w[2][i].y, hv.y, a2);
      a2 = fmaf(w[2][i].z, hv.z, a2); a2 = fmaf(w[2][i].w, hv.w, a2);
      a3 = fmaf(w[3][i].x, hv.x, a3); a3 = fmaf(w[3][i].y, hv.y, a3);
      a3 = fmaf(w[3][i].z, hv.z, a3); a3 = fmaf(w[3][i].w, hv.w, a3);
    }
#pragma unroll
    for (int m = 1; m <= 8; m <<= 1) {
      a0 += __shfl_xor(a0, m, 64);
      a1 += __shfl_xor(a1, m, 64);
      a2 += __shfl_xor(a2, m, 64);
      a3 += __shfl_xor(a3, m, 64);
    }

    // E. publish h_t (16 contiguous tagged words per wave, one instruction)
    if (cg < 4) {
      const float acc = (cg == 0) ? a0 : (cg == 1) ? a1 : (cg == 2) ? a2 : a3;
      const float h = fmaxf(acc + bias, 0.f);
      const int j = j0 + cg;
      union { float f; unsigned int u; } cv; cv.f = h;
      const unsigned long long tag = (unsigned long long)(unsigned int)t << 32;
      unsigned long long* sb = (t & 1) ? stg1 : stg0;
      __hip_atomic_store(&sb[j], tag | cv.u,
                         __ATOMIC_RELAXED, __HIP_MEMORY_SCOPE_AGENT);
      __builtin_nontemporal_store(h, &o_t[j]);  // output[t,b,j]
      hbuf[t & 1][j] = h;    // own rows for next step
      hlast = h;
    }
  }

  // h_final = h_{T-1}
  if (cg < 4) {
    __builtin_nontemporal_store(
        hlast, &out[(size_t)T_DIM * BH_DIM + (size_t)b * H_DIM + j0 + cg]);
  }
}

extern "C" void kernel_launch(void* const* d_in, const int* in_sizes, int n_in,
                              void* d_out, int out_size, void* d_ws, size_t ws_size,
                              hipStream_t stream) {
  const float* x   = (const float*)d_in[0];  // [T,B,I]
  const float* wih = (const float*)d_in[1];  // [H,I]
  const float* whh = (const float*)d_in[2];  // [H,H]
  const float* bih = (const float*)d_in[3];  // [H]
  const float* bhh = (const float*)d_in[4];  // [H]
  float* out = (float*)d_out;                // [T,B,H] output ++ [B,H] h_final
  // staging: 2 parities x 64 batches x 512 tagged 8B words = 512 KB
  unsigned long long* stage = (unsigned long long*)d_ws;

  rnn_fused<<<256, 512, 0, stream>>>(x, wih, whh, bih, bhh, out, stage);
}

// Round 5
// 887.848 us; speedup vs baseline: 1.2122x; 1.1050x over previous
//
#include <hip/hip_runtime.h>

// Problem constants (fixed by the reference): T=512, B=64, I=256, H=512.
#define T_DIM 512
#define B_DIM 64
#define I_DIM 256
#define H_DIM 512
#define BH_DIM (B_DIM * H_DIM)   // 32768

// ---------------------------------------------------------------------------
// Round-11: two kernels.
//
// R6/R8 re-analysis: the 4400cy step period is DS-PIPE occupancy, not
// protocol latency. Per CU/step: ih 160 b128 + hh 64 b128 + 256 ds_swizzle
// (__shfl_xor!) ~= 2800-4200cy. The fabric round trip hides under it.
// So: (1) hoist the ih-matvec into a pre-pass GEMM writing xw into `out`
// itself (out is [T,B,H]; scan reads xw[t,b,j] strictly before writing
// h[t,b,j] from the same lane); (2) replace the butterfly's DS-swizzles
// with DPP adds on the VALU pipe (quad_perm + row_ror). Scan loop DS work
// drops ~5x; LDS shrinks to 4KB; protocol identical to proven R8 (agent-
// scope tagged words), plus tag+1 so poisoned stage can't alias a publish.
//
// Kernel 1 (xw_gemm): xw[m,n] = sum_k x[m,k]*wih[n,k] + bih[n] + bhh[n],
//   m = t*64+b in [0,32768), n in [0,512). 128x128 tiles, BK=32, 256 thr,
//   8x8 micro-tile. FMA floor ~55us.
// Kernel 2 (rnn_scan): 256 blocks = 4 row-chunks x 64 batches, 512 thr,
//   W_hh chunk in regs (w[4][8]); per step: poll 384 partner h words ->
//   LDS; barrier; hh-fma; DPP reduce; h = relu(acc + xw); publish.
// ---------------------------------------------------------------------------

// ---------------- Kernel 1: xw pre-pass GEMM ----------------
__global__ __launch_bounds__(256) void xw_gemm(
    const float* __restrict__ x, const float* __restrict__ wih,
    const float* __restrict__ bih, const float* __restrict__ bhh,
    float* __restrict__ out) {
  __shared__ __align__(16) float As[32][128];  // [k][m]
  __shared__ __align__(16) float Bs[32][128];  // [k][n]

  const int bm = blockIdx.x >> 2;   // 0..255 (m-tile)
  const int bn = blockIdx.x & 3;    // 0..3   (n-tile) - fastest: A-tile L2 reuse
  const int m0 = bm * 128, n0 = bn * 128;
  const int tid = threadIdx.x;      // 0..255
  const int tx = tid & 15, ty = tid >> 4;
  const int ml = tid & 127, kq = tid >> 7;  // staging map

  float acc[8][8];
#pragma unroll
  for (int r = 0; r < 8; r++)
#pragma unroll
    for (int c = 0; c < 8; c++) acc[r][c] = 0.f;

  for (int kc = 0; kc < I_DIM; kc += 32) {
    // global loads (issued before barrier -> latency overlaps the wait)
    const float4* xr = (const float4*)(x + (size_t)(m0 + ml) * I_DIM + kc + kq * 16);
    const float4* br = (const float4*)(wih + (size_t)(n0 + ml) * I_DIM + kc + kq * 16);
    float4 av[4], bv[4];
#pragma unroll
    for (int j = 0; j < 4; j++) { av[j] = xr[j]; bv[j] = br[j]; }

    __syncthreads();  // previous chunk's compute done before overwrite
#pragma unroll
    for (int j = 0; j < 4; j++) {
      const int k = kq * 16 + j * 4;
      As[k + 0][ml] = av[j].x; As[k + 1][ml] = av[j].y;
      As[k + 2][ml] = av[j].z; As[k + 3][ml] = av[j].w;
      Bs[k + 0][ml] = bv[j].x; Bs[k + 1][ml] = bv[j].y;
      Bs[k + 2][ml] = bv[j].z; Bs[k + 3][ml] = bv[j].w;
    }
    __syncthreads();

#pragma unroll 4
    for (int kk = 0; kk < 32; kk++) {
      const float4 a0 = *(const float4*)&As[kk][ty * 4];
      const float4 a1 = *(const float4*)&As[kk][64 + ty * 4];
      const float4 b0 = *(const float4*)&Bs[kk][tx * 4];
      const float4 b1 = *(const float4*)&Bs[kk][64 + tx * 4];
      const float ar[8] = {a0.x, a0.y, a0.z, a0.w, a1.x, a1.y, a1.z, a1.w};
      const float br_[8] = {b0.x, b0.y, b0.z, b0.w, b1.x, b1.y, b1.z, b1.w};
#pragma unroll
      for (int r = 0; r < 8; r++)
#pragma unroll
        for (int c = 0; c < 8; c++) acc[r][c] = fmaf(ar[r], br_[c], acc[r][c]);
    }
  }

  // bias add + store
  const float4 bi0 = *(const float4*)(bih + n0 + tx * 4);
  const float4 bh0 = *(const float4*)(bhh + n0 + tx * 4);
  const float4 bi1 = *(const float4*)(bih + n0 + 64 + tx * 4);
  const float4 bh1 = *(const float4*)(bhh + n0 + 64 + tx * 4);
  const float4 bb0 = make_float4(bi0.x + bh0.x, bi0.y + bh0.y, bi0.z + bh0.z, bi0.w + bh0.w);
  const float4 bb1 = make_float4(bi1.x + bh1.x, bi1.y + bh1.y, bi1.z + bh1.z, bi1.w + bh1.w);

#pragma unroll
  for (int r = 0; r < 8; r++) {
    const int m = m0 + ((r < 4) ? (ty * 4 + r) : (64 + ty * 4 + (r - 4)));
    float4* orow = (float4*)(out + (size_t)m * H_DIM + n0);
    orow[tx] = make_float4(acc[r][0] + bb0.x, acc[r][1] + bb0.y,
                           acc[r][2] + bb0.z, acc[r][3] + bb0.w);
    orow[16 + tx] = make_float4(acc[r][4] + bb1.x, acc[r][5] + bb1.y,
                                acc[r][6] + bb1.z, acc[r][7] + bb1.w);
  }
}

// ---------------- Kernel 2: recurrent scan ----------------

// 16-lane sum on the VALU pipe (DPP), no DS traffic. All 16 lanes of each
// row end with the full sum. quad_perm[1,0,3,2]=0xB1, [2,3,0,1]=0x4E,
// row_ror:4=0x124, row_ror:8=0x128.
__device__ __forceinline__ float row16_sum(float v) {
  int m;
  m = __builtin_amdgcn_update_dpp(0, __float_as_int(v), 0xB1, 0xF, 0xF, true);
  v += __int_as_float(m);
  m = __builtin_amdgcn_update_dpp(0, __float_as_int(v), 0x4E, 0xF, 0xF, true);
  v += __int_as_float(m);
  m = __builtin_amdgcn_update_dpp(0, __float_as_int(v), 0x124, 0xF, 0xF, true);
  v += __int_as_float(m);
  m = __builtin_amdgcn_update_dpp(0, __float_as_int(v), 0x128, 0xF, 0xF, true);
  v += __int_as_float(m);
  return v;
}

__global__ __launch_bounds__(512, 2) void rnn_scan(
    const float* __restrict__ whh, float* __restrict__ out,
    unsigned long long* __restrict__ stage) {
  __shared__ __align__(16) float hbuf[2][H_DIM];  // 4 KB h double buffer

  const int b   = blockIdx.x & 63;
  const int rb  = blockIdx.x >> 6;       // row-chunk 0..3
  const int tid = threadIdx.x;           // 0..511
  const int rg  = tid >> 4;              // 0..31
  const int cg  = tid & 15;              // 0..15
  const int j0  = rb * 128 + rg * 4;     // first of my 4 rows

  // spin target: one partner element each for threads 0..383 (skip own chunk)
  const int pj = (tid < rb * 128) ? tid : tid + 128;

  // ---- W_hh chunk -> registers (once) ----
  float4 w[4][8];
#pragma unroll
  for (int r = 0; r < 4; r++) {
    const float4* wr = (const float4*)(whh + (size_t)(j0 + r) * H_DIM);
#pragma unroll
    for (int i = 0; i < 8; i++) w[r][i] = wr[i * 16 + cg];
  }

  float* __restrict__ outb = out + (size_t)b * H_DIM;  // t-stride = BH_DIM
  unsigned long long* __restrict__ stg0 = stage + (size_t)b * H_DIM;
  unsigned long long* __restrict__ stg1 = stage + (size_t)(64 + b) * H_DIM;

  float hlast = 0.f;

  // ---- t = 0: h_0 = relu(xw_0); publish (tag 1, parity 0) ----
  if (cg < 4) {
    const int j = j0 + cg;
    const float h = fmaxf(__builtin_nontemporal_load(&outb[j]), 0.f);
    union { float f; unsigned int u; } cv; cv.f = h;
    __hip_atomic_store(&stg0[j], (1ULL << 32) | (unsigned long long)cv.u,
                       __ATOMIC_RELAXED, __HIP_MEMORY_SCOPE_AGENT);
    __builtin_nontemporal_store(h, &outb[j]);
    hbuf[0][j] = h;
    hlast = h;
  }

  // ---- main scan ----
  for (int t = 1; t < T_DIM; t++) {
    const int p = (t - 1) & 1;  // parity of h_{t-1}
    float* hb = hbuf[p];
    float* o_t = outb + (size_t)t * BH_DIM;

    // A. spin-collect the 384 partner elements of h_{t-1} into LDS.
    //    h_{t-1} carries tag t (tags offset +1: poison can't alias).
    if (tid < 384) {
      unsigned long long* slot = (p ? stg1 : stg0) + pj;
      const unsigned int want = (unsigned int)t;
      unsigned long long v;
      do {
        v = __hip_atomic_load(slot, __ATOMIC_RELAXED, __HIP_MEMORY_SCOPE_AGENT);
      } while ((unsigned int)(v >> 32) != want);
      union { unsigned int u; float f; } cv; cv.u = (unsigned int)v;
      hb[pj] = cv.f;
    }

    // B. xw prefetch for my rows (issued post-poll: latency hides under
    //    barrier + hh-fma; value consumed at publish)
    float xwv = 0.f;
    if (cg < 4) xwv = __builtin_nontemporal_load(&o_t[j0 + cg]);

    __syncthreads();  // h_{t-1} complete in LDS (single barrier per step)

    // C. hh-fma: 4 rows x 8 float4 per thread (W_hh in regs)
    float a0 = 0.f, a1 = 0.f, a2 = 0.f, a3 = 0.f;
#pragma unroll
    for (int i = 0; i < 8; i++) {
      const float4 hv = ((const float4*)hb)[i * 16 + cg];
      a0 = fmaf(w[0][i].x, hv.x, a0); a0 = fmaf(w[0][i].y, hv.y, a0);
      a0 = fmaf(w[0][i].z, hv.z, a0); a0 = fmaf(w[0][i].w, hv.w, a0);
      a1 = fmaf(w[1][i].x, hv.x, a1); a1 = fmaf(w[1][i].y, hv.y, a1);
      a1 = fmaf(w[1][i].z, hv.z, a1); a1 = fmaf(w[1][i].w, hv.w, a1);
      a2 = fmaf(w[2][i].x, hv.x, a2); a2 = fmaf(w[2][i].y, hv.y, a2);
      a2 = fmaf(w[2][i].z, hv.z, a2); a2 = fmaf(w[2][i].w, hv.w, a2);
      a3 = fmaf(w[3][i].x, hv.x, a3); a3 = fmaf(w[3][i].y, hv.y, a3);
      a3 = fmaf(w[3][i].z, hv.z, a3); a3 = fmaf(w[3][i].w, hv.w, a3);
    }

    // D. 16-lane reduce on VALU pipe (DPP) -- no DS traffic
    a0 = row16_sum(a0);
    a1 = row16_sum(a1);
    a2 = row16_sum(a2);
    a3 = row16_sum(a3);

    // E. publish h_t (tag t+1; 16 contiguous tagged words per wave)
    if (cg < 4) {
      const float acc = (cg == 0) ? a0 : (cg == 1) ? a1 : (cg == 2) ? a2 : a3;
      const float h = fmaxf(acc + xwv, 0.f);
      const int j = j0 + cg;
      union { float f; unsigned int u; } cv; cv.f = h;
      const unsigned long long val =
          ((unsigned long long)(unsigned int)(t + 1) << 32) |
          (unsigned long long)cv.u;
      unsigned long long* sb = (t & 1) ? stg1 : stg0;
      __hip_atomic_store(&sb[j], val, __ATOMIC_RELAXED,
                         __HIP_MEMORY_SCOPE_AGENT);
      __builtin_nontemporal_store(h, &o_t[j]);  // overwrite xw slot with h
      hbuf[t & 1][j] = h;    // own rows for next step
      hlast = h;
    }
  }

  // h_final = h_{T-1}
  if (cg < 4) {
    __builtin_nontemporal_store(
        hlast, &out[(size_t)T_DIM * BH_DIM + (size_t)b * H_DIM + j0 + cg]);
  }
}

extern "C" void kernel_launch(void* const* d_in, const int* in_sizes, int n_in,
                              void* d_out, int out_size, void* d_ws, size_t ws_size,
                              hipStream_t stream) {
  const float* x   = (const float*)d_in[0];  // [T,B,I]
  const float* wih = (const float*)d_in[1];  // [H,I]
  const float* whh = (const float*)d_in[2];  // [H,H]
  const float* bih = (const float*)d_in[3];  // [H]
  const float* bhh = (const float*)d_in[4];  // [H]
  float* out = (float*)d_out;                // [T,B,H] output ++ [B,H] h_final
  // staging: 2 parities x 64 batches x 512 tagged 8B words = 512 KB
  unsigned long long* stage = (unsigned long long*)d_ws;

  // Pass 1: xw = x @ wih^T + bih + bhh  -> written into out[0 .. T*B*H)
  xw_gemm<<<1024, 256, 0, stream>>>(x, wih, bih, bhh, out);
  // Pass 2: recurrent scan, reads xw from out and overwrites with h
  rnn_scan<<<256, 512, 0, stream>>>(whh, out, stage);
}